// Round 4
// baseline (2616.246 us; speedup 1.0000x reference)
//
#include <hip/hip_runtime.h>
#include <hip/hip_fp16.h>

// ---------------------------------------------------------------------------
// VPTQ quantize + linear:  out = X @ quantize(W)^T + bias
//   X: [16384, 4096] f32   W: [4096, 4096] f32   centroids: [256, 8] f32
//   out: [16384, 4096] f32
// Strategy: fp16 hi/lo split GEMM (3-term: hi*hi + hi*lo + lo*hi) on MFMA.
// Scheme error ~2^-22 relative == fp32-grade accuracy at ~3x bf16-GEMM cost.
// ---------------------------------------------------------------------------

typedef _Float16 half8 __attribute__((ext_vector_type(8)));
typedef float f32x4 __attribute__((ext_vector_type(4)));

#define AS1 __attribute__((address_space(1)))
#define AS3 __attribute__((address_space(3)))

static constexpr int M_DIM = 16384;   // 4 * 4096 rows of x
static constexpr int N_DIM = 4096;    // output features
static constexpr int K_DIM = 4096;    // reduction
static constexpr float EPSF = 1e-8f;

__device__ __forceinline__ void gl_lds16(const _Float16* g, _Float16* l) {
  // async global->LDS DMA, 16B per lane; LDS dest = wave-uniform base + lane*16
  __builtin_amdgcn_global_load_lds((const AS1 void*)g, (AS3 void*)l, 16, 0, 0);
}

// ---------------- x: fp32 -> f16 hi + f16 lo (8 elems / thread) ------------
__global__ __launch_bounds__(256) void split_x_kernel(const float* __restrict__ x,
                                                      _Float16* __restrict__ hi,
                                                      _Float16* __restrict__ lo) {
  size_t i = (size_t)blockIdx.x * blockDim.x + threadIdx.x;
  const float4* xv = (const float4*)x;
  float4 v0 = xv[i * 2];
  float4 v1 = xv[i * 2 + 1];
  float v[8] = {v0.x, v0.y, v0.z, v0.w, v1.x, v1.y, v1.z, v1.w};
  half8 h, l;
#pragma unroll
  for (int j = 0; j < 8; ++j) {
    _Float16 hj = (_Float16)v[j];
    h[j] = hj;
    l[j] = (_Float16)(v[j] - (float)hj);
  }
  ((half8*)hi)[i] = h;
  ((half8*)lo)[i] = l;
}

// ---------------- VQ quantize: one thread per 8-element vector -------------
template <bool F16OUT>
__global__ __launch_bounds__(256) void quantize_kernel(const float* __restrict__ weight,
                                                       const float* __restrict__ centroids,
                                                       _Float16* __restrict__ qhi,
                                                       _Float16* __restrict__ qlo,
                                                       float* __restrict__ qf32) {
  __shared__ float cent[256][8];
  __shared__ float cnorm[256];
  const int t = threadIdx.x;
  {
    float4 c0 = ((const float4*)centroids)[t * 2];
    float4 c1 = ((const float4*)centroids)[t * 2 + 1];
    cent[t][0] = c0.x; cent[t][1] = c0.y; cent[t][2] = c0.z; cent[t][3] = c0.w;
    cent[t][4] = c1.x; cent[t][5] = c1.y; cent[t][6] = c1.z; cent[t][7] = c1.w;
    cnorm[t] = c0.x * c0.x + c0.y * c0.y + c0.z * c0.z + c0.w * c0.w +
               c1.x * c1.x + c1.y * c1.y + c1.z * c1.z + c1.w * c1.w;
  }
  __syncthreads();

  size_t vid = (size_t)blockIdx.x * 256 + t;
  float4 w0 = ((const float4*)weight)[vid * 2];
  float4 w1 = ((const float4*)weight)[vid * 2 + 1];
  float v[8] = {w0.x, w0.y, w0.z, w0.w, w1.x, w1.y, w1.z, w1.w};

  float nn = 0.f;
#pragma unroll
  for (int j = 0; j < 8; ++j) nn += v[j] * v[j];
  float norm = sqrtf(nn) + EPSF;   // matches jnp.linalg.norm + EPS
  float n[8];
  float nn2 = 0.f;
#pragma unroll
  for (int j = 0; j < 8; ++j) { n[j] = v[j] / norm; nn2 += n[j] * n[j]; }

  // d2 = |n|^2 - 2 n.c + |c|^2, first strict min (matches jnp.argmin)
  float best = 3.4e38f;
  int bi = 0;
  for (int k = 0; k < 256; ++k) {
    float dot = 0.f;
#pragma unroll
    for (int j = 0; j < 8; ++j) dot += n[j] * cent[k][j];  // LDS broadcast
    float d2 = nn2 - 2.f * dot + cnorm[k];
    if (d2 < best) { best = d2; bi = k; }
  }

  float num = 0.f, den = 0.f;
  float a[8];
#pragma unroll
  for (int j = 0; j < 8; ++j) {
    a[j] = cent[bi][j];
    num += v[j] * a[j];
    den += a[j] * a[j];
  }
  float s = num / (den + EPSF);

  if (F16OUT) {
    half8 h, l;
#pragma unroll
    for (int j = 0; j < 8; ++j) {
      float q = a[j] * s;
      _Float16 hj = (_Float16)q;
      h[j] = hj;
      l[j] = (_Float16)(q - (float)hj);
    }
    ((half8*)qhi)[vid] = h;
    ((half8*)qlo)[vid] = l;
  } else {
    float4 q0, q1;
    q0.x = a[0] * s; q0.y = a[1] * s; q0.z = a[2] * s; q0.w = a[3] * s;
    q1.x = a[4] * s; q1.y = a[5] * s; q1.z = a[6] * s; q1.w = a[7] * s;
    ((float4*)qf32)[vid * 2] = q0;
    ((float4*)qf32)[vid * 2 + 1] = q1;
  }
}

// ---------------- split GEMM: C = Xhl * Qhl^T + bias, 3-term f16 MFMA ------
// 128x128 tile, BK=32, 256 threads (4 waves as 2x2 of 64x64), m97 structure:
// global_load_lds(16B) staging -> barrier -> ds_read_b128 frags -> 48 MFMA.
// XCD-aware bijective block swizzle (T1): nwg=4096, nwg%8==0.
__global__ __launch_bounds__(256, 2) void gemm_split_kernel(
    const _Float16* __restrict__ xhi, const _Float16* __restrict__ xlo,
    const _Float16* __restrict__ qhi, const _Float16* __restrict__ qlo,
    const float* __restrict__ bias, float* __restrict__ out) {
  __shared__ __align__(16) _Float16 sAhi[128 * 32];
  __shared__ __align__(16) _Float16 sAlo[128 * 32];
  __shared__ __align__(16) _Float16 sBhi[128 * 32];
  __shared__ __align__(16) _Float16 sBlo[128 * 32];

  const int t = threadIdx.x;
  const int lane = t & 63;
  const int w = t >> 6;            // wave 0..3
  const int wm = w >> 1, wn = w & 1;

  // XCD swizzle: dispatch id -> contiguous work chunk per XCD (bijective, 4096%8==0)
  const int nbx = N_DIM / 128;                       // 32
  const int id = blockIdx.y * nbx + blockIdx.x;      // dispatch order, x fastest
  const int swz = (id & 7) * (4096 / 8) + (id >> 3); // chunk of 512 per XCD
  const int bm = (swz / nbx) * 128;
  const int bn = (swz % nbx) * 128;

  // staging geometry: each gl_lds16 issue covers 16 rows (64 lanes * 16B = 1KB)
  const int srow = lane >> 2;          // 0..15 row within 16-row segment
  const int scol = (lane & 3) * 8;     // halves: 16B chunk within 64B row

  const _Float16* gAhi = xhi + (size_t)(bm + srow) * K_DIM + scol;
  const _Float16* gAlo = xlo + (size_t)(bm + srow) * K_DIM + scol;
  const _Float16* gBhi = qhi + (size_t)(bn + srow) * K_DIM + scol;
  const _Float16* gBlo = qlo + (size_t)(bn + srow) * K_DIM + scol;

  f32x4 acc[4][4] = {};

  const int fr = lane & 15;            // fragment row/col within 16
  const int fk = (lane >> 4) * 8;      // k-offset (halves)

  for (int k0 = 0; k0 < K_DIM; k0 += 32) {
#pragma unroll
    for (int i = 0; i < 2; ++i) {
      const int seg = w * 2 + i;                       // 0..7: 16-row segment
      const size_t go = (size_t)seg * 16 * K_DIM + k0; // global row offset
      const int lofs = seg * 512;                      // halves: 16 rows * 32
      gl_lds16(gAhi + go, sAhi + lofs);
      gl_lds16(gAlo + go, sAlo + lofs);
      gl_lds16(gBhi + go, sBhi + lofs);
      gl_lds16(gBlo + go, sBlo + lofs);
    }
    __syncthreads();   // vmcnt(0) drain + barrier: tiles visible

    half8 ah[4], al[4], bh[4], bl[4];
#pragma unroll
    for (int mi = 0; mi < 4; ++mi) {
      const int r = wm * 64 + mi * 16 + fr;
      ah[mi] = *(const half8*)&sAhi[r * 32 + fk];
      al[mi] = *(const half8*)&sAlo[r * 32 + fk];
    }
#pragma unroll
    for (int nj = 0; nj < 4; ++nj) {
      const int r = wn * 64 + nj * 16 + fr;
      bh[nj] = *(const half8*)&sBhi[r * 32 + fk];
      bl[nj] = *(const half8*)&sBlo[r * 32 + fk];
    }
#pragma unroll
    for (int mi = 0; mi < 4; ++mi)
#pragma unroll
      for (int nj = 0; nj < 4; ++nj) {
        acc[mi][nj] = __builtin_amdgcn_mfma_f32_16x16x32_f16(ah[mi], bh[nj], acc[mi][nj], 0, 0, 0);
        acc[mi][nj] = __builtin_amdgcn_mfma_f32_16x16x32_f16(ah[mi], bl[nj], acc[mi][nj], 0, 0, 0);
        acc[mi][nj] = __builtin_amdgcn_mfma_f32_16x16x32_f16(al[mi], bh[nj], acc[mi][nj], 0, 0, 0);
      }
    __syncthreads();   // before next staging overwrites
  }

  // epilogue: C/D layout col = lane&15, row = (lane>>4)*4 + reg
#pragma unroll
  for (int nj = 0; nj < 4; ++nj) {
    const int col = bn + wn * 64 + nj * 16 + fr;
    const float bv = bias[col];
#pragma unroll
    for (int mi = 0; mi < 4; ++mi) {
      const int row0 = bm + wm * 64 + mi * 16 + (lane >> 4) * 4;
#pragma unroll
      for (int r = 0; r < 4; ++r) {
        out[(size_t)(row0 + r) * N_DIM + col] = acc[mi][nj][r] + bv;
      }
    }
  }
}

// ---------------- fallback fp32 GEMM (only if ws too small) ----------------
__global__ __launch_bounds__(256) void gemm_f32_kernel(const float* __restrict__ X,
                                                       const float* __restrict__ Q,
                                                       const float* __restrict__ bias,
                                                       float* __restrict__ out) {
  __shared__ float sA[64][33];
  __shared__ float sB[64][33];
  const int tx = threadIdx.x & 15, ty = threadIdx.x >> 4;
  const int bm = blockIdx.y * 64, bn = blockIdx.x * 64;
  float acc[4][4] = {};
  const int lr = threadIdx.x >> 2;          // 0..63
  const int lc = (threadIdx.x & 3) * 8;     // 0,8,16,24
  for (int k0 = 0; k0 < K_DIM; k0 += 32) {
    float4 a0 = *(const float4*)&X[(size_t)(bm + lr) * K_DIM + k0 + lc];
    float4 a1 = *(const float4*)&X[(size_t)(bm + lr) * K_DIM + k0 + lc + 4];
    float4 b0 = *(const float4*)&Q[(size_t)(bn + lr) * K_DIM + k0 + lc];
    float4 b1 = *(const float4*)&Q[(size_t)(bn + lr) * K_DIM + k0 + lc + 4];
    sA[lr][lc + 0] = a0.x; sA[lr][lc + 1] = a0.y; sA[lr][lc + 2] = a0.z; sA[lr][lc + 3] = a0.w;
    sA[lr][lc + 4] = a1.x; sA[lr][lc + 5] = a1.y; sA[lr][lc + 6] = a1.z; sA[lr][lc + 7] = a1.w;
    sB[lr][lc + 0] = b0.x; sB[lr][lc + 1] = b0.y; sB[lr][lc + 2] = b0.z; sB[lr][lc + 3] = b0.w;
    sB[lr][lc + 4] = b1.x; sB[lr][lc + 5] = b1.y; sB[lr][lc + 6] = b1.z; sB[lr][lc + 7] = b1.w;
    __syncthreads();
#pragma unroll 8
    for (int kk = 0; kk < 32; ++kk) {
      float av[4], bv[4];
#pragma unroll
      for (int i = 0; i < 4; ++i) av[i] = sA[ty * 4 + i][kk];
#pragma unroll
      for (int j = 0; j < 4; ++j) bv[j] = sB[tx * 4 + j][kk];
#pragma unroll
      for (int i = 0; i < 4; ++i)
#pragma unroll
        for (int j = 0; j < 4; ++j) acc[i][j] += av[i] * bv[j];
    }
    __syncthreads();
  }
#pragma unroll
  for (int i = 0; i < 4; ++i)
#pragma unroll
    for (int j = 0; j < 4; ++j)
      out[(size_t)(bm + ty * 4 + i) * N_DIM + bn + tx * 4 + j] = acc[i][j] + bias[bn + tx * 4 + j];
}

// ---------------------------------------------------------------------------
extern "C" void kernel_launch(void* const* d_in, const int* in_sizes, int n_in,
                              void* d_out, int out_size, void* d_ws, size_t ws_size,
                              hipStream_t stream) {
  const float* x = (const float*)d_in[0];
  const float* weight = (const float*)d_in[1];
  const float* bias = (const float*)d_in[2];
  const float* centroids = (const float*)d_in[3];
  float* out = (float*)d_out;

  const size_t XE = (size_t)M_DIM * K_DIM;  // 67108864 x elements
  const size_t QE = (size_t)N_DIM * K_DIM;  // 16777216 weight elements
  const size_t need_split = XE * 2 * sizeof(_Float16) + QE * 2 * sizeof(_Float16); // 320 MiB

  if (ws_size >= need_split) {
    _Float16* xhi = (_Float16*)d_ws;
    _Float16* xlo = xhi + XE;
    _Float16* qhi = xlo + XE;
    _Float16* qlo = qhi + QE;

    split_x_kernel<<<dim3((unsigned)(XE / 8 / 256)), dim3(256), 0, stream>>>(x, xhi, xlo);
    quantize_kernel<true><<<dim3((unsigned)(QE / 8 / 256)), dim3(256), 0, stream>>>(
        weight, centroids, qhi, qlo, nullptr);
    gemm_split_kernel<<<dim3(N_DIM / 128, M_DIM / 128), dim3(256), 0, stream>>>(
        xhi, xlo, qhi, qlo, bias, out);
  } else {
    // fallback: fp32 path, needs 64 MiB for q_weight
    float* qw = (float*)d_ws;
    quantize_kernel<false><<<dim3((unsigned)(QE / 8 / 256)), dim3(256), 0, stream>>>(
        weight, centroids, nullptr, nullptr, qw);
    gemm_f32_kernel<<<dim3(N_DIM / 64, M_DIM / 64), dim3(256), 0, stream>>>(x, qw, bias, out);
  }
}